// Round 5
// baseline (342.347 us; speedup 1.0000x reference)
//
#include <hip/hip_runtime.h>
#include <hip/hip_bf16.h>

// Dipole: day-emb GEMM -> fwd GRU + 64 reverse GRUs -> masked softmax attention -> 2-layer head.
// T=64 B=32 D_IN=4096 D_DAY=H=256 D_OUT=942.
//
//  k4 gru_recurrent : 8-wave R3 version (118us, near phase-serial bound -- parked).
//  gemm_k           : R5: BARRIER-FREE direct-frag GEMM. R4 post-mortem: vmcnt is in-order,
//                     so the staged-LDS pipeline never had hidden slack; the LDS commit +
//                     2 barriers per 64-wide K-step serialized every iteration. For M=32
//                     tiles the A-frag is 16 contiguous bytes at A[row=c][quad*8] -- load it
//                     straight from global (16 rows x 64B = 16 full lines/wave), delete As/
//                     barriers entirely, #pragma unroll so loads hoist across K-steps.
//                     Waves fully independent -> latency hidden by ILP+TLP.
// All other kernels identical to R3.

typedef __bf16 bf16x8 __attribute__((ext_vector_type(8)));
typedef __bf16 bf16x4 __attribute__((ext_vector_type(4)));
typedef float  f32x4  __attribute__((ext_vector_type(4)));
typedef int    int4v  __attribute__((ext_vector_type(4)));

static constexpr float NEG_L2E = -1.442695041f;   // -log2(e)
static constexpr float TWO_L2E =  2.885390082f;   //  2*log2(e)

// ---------------- workspace layout (bytes) ----------------
static constexpr size_t OFF_PK_EMB = 0;                        // 256x4096 bf16    = 2097152
static constexpr size_t OFF_PK_IH  = 2097152;                  // 1536x256 bf16    =  786432
static constexpr size_t OFF_WQ     = 2883584;                  // 2x768x256 int8   =  393216
static constexpr size_t OFF_WSC    = 3276800;                  // 1536 f32         =    6144
static constexpr size_t OFF_PK_AO  = 3670016;                  // 256x1024 bf16    =  524288
static constexpr size_t OFF_PK_O   = 4194304;                  // 960x256 bf16     =  491520
static constexpr size_t OFF_DAY    = 4685824;                  // 2048x256 bf16    = 1048576
static constexpr size_t OFF_GIT    = 5734400;                  // 2048x1536 bf16   = 6291456
static constexpr size_t OFF_BC     = 12025856;                 // 1536 f32         =    6144
static constexpr size_t OFF_REV    = 18317312;                 // 2080*32*256 bf16 = 34078720
static constexpr size_t OFF_FWD    = 52396032;                 // 64*32*256 bf16   = 1048576
static constexpr size_t OFF_HT     = 53444608;                 // 2048x1024 bf16   = 4194304
static constexpr size_t OFF_TMP1   = 57638912;                 // 2048x256 bf16    = 1048576
// xb (2048x4096 bf16 = 16.7MB) aliases OFF_REV: dead before gru_recurrent writes rev.
static constexpr size_t OFF_XB     = OFF_REV;

__device__ __forceinline__ float sigf(float x) {
    return __builtin_amdgcn_rcpf(1.f + __expf(-x));
}

// lgkmcnt-only barrier: does NOT drain vmcnt.
#define LDS_BARRIER() asm volatile("s_waitcnt lgkmcnt(0)\n\ts_barrier" ::: "memory")

// ---------------- fused packer: bf16 frags + x->bf16 + Whh int8 + bias ----------------
// bf16 frag layout: flat = ((nt*K32+ks)*64+lane)*8+j holds W[nt*16+lane%16][ks*32+(lane/16)*8+j]
// i8 frag (A/B lane-symmetric): (n,k): lane=(n&15)|(((k>>4)&3)<<4), byte j=k&15;
//   flat = dir*196608 + ((n>>4)*4 + (k>>6))*1024 + lane*16 + j.
__global__ __launch_bounds__(256) void pack_misc(
    const float* __restrict__ We,  const float* __restrict__ Wir, const float* __restrict__ Wif,
    const float* __restrict__ Wao, const float* __restrict__ Wo,  const float* __restrict__ x,
    const float* __restrict__ Whr, const float* __restrict__ Whf,
    const float* __restrict__ bih_r, const float* __restrict__ bih_f,
    const float* __restrict__ bhh_r, const float* __restrict__ bhh_f,
    __bf16* pe, __bf16* pi, __bf16* pao, __bf16* po, __bf16* xb,
    signed char* __restrict__ wq, float* __restrict__ wscale, float* __restrict__ bc)
{
    int b = blockIdx.x;
    if (b >= 5048) {                      // Whh int8 pack: 4 rows per block (one per wave)
        int rowb = (b - 5048) * 4 + (threadIdx.x >> 6);   // 0..1535: dir*768 + n
        int t = threadIdx.x & 63;
        int dir = (rowb >= 768) ? 1 : 0;
        int n = rowb - dir * 768;
        const float* src = (dir ? Whf : Whr) + (size_t)n * 256;
        float4 wv = ((const float4*)src)[t];
        float m = fmaxf(fmaxf(fabsf(wv.x), fabsf(wv.y)), fmaxf(fabsf(wv.z), fabsf(wv.w)));
#pragma unroll
        for (int off = 32; off > 0; off >>= 1) m = fmaxf(m, __shfl_xor(m, off));
        m = fmaxf(m, 1e-20f);
        float inv = 127.f / m;
        int q0 = (int)__builtin_rintf(wv.x * inv);
        int q1 = (int)__builtin_rintf(wv.y * inv);
        int q2 = (int)__builtin_rintf(wv.z * inv);
        int q3 = (int)__builtin_rintf(wv.w * inv);
        int pk = (q0 & 0xff) | ((q1 & 0xff) << 8) | ((q2 & 0xff) << 16) | ((q3 & 0xff) << 24);
        int dlane = (n & 15) | (((t >> 2) & 3) << 4);
        size_t byte = (size_t)dir * 196608 + ((size_t)(n >> 4) * 4 + (t >> 4)) * 1024
                    + (size_t)dlane * 16 + (t & 3) * 4;
        *(int*)(wq + byte) = pk;
        if (t == 0) {
            float gc = (n < 512) ? NEG_L2E : TWO_L2E;
            wscale[rowb] = m * (1.f / 16129.f) * gc;
            const float* bi = dir ? bih_f : bih_r;
            const float* bh = dir ? bhh_f : bhh_r;
            bc[rowb] = (n < 512) ? (bi[n] + bh[n]) * NEG_L2E : bi[n] * TWO_L2E;
        }
        return;
    }
    if (b >= 952) {                       // x -> bf16 (8 elems/thread)
        size_t base = ((size_t)(b - 952) * 256 + threadIdx.x) * 8;
        float4 v0 = *(const float4*)(x + base);
        float4 v1 = *(const float4*)(x + base + 4);
        bf16x8 o;
        o[0]=(__bf16)v0.x; o[1]=(__bf16)v0.y; o[2]=(__bf16)v0.z; o[3]=(__bf16)v0.w;
        o[4]=(__bf16)v1.x; o[5]=(__bf16)v1.y; o[6]=(__bf16)v1.z; o[7]=(__bf16)v1.w;
        *(bf16x8*)(xb + base) = o;
        return;
    }
    const float* src; __bf16* dst; int Nsrc, k32l, b0; bool ih = false;
    if (b < 512)      { src = We;  dst = pe;          Nsrc = 256; k32l = 7; b0 = 0;   }
    else if (b < 608) { src = Wir; dst = pi;          Nsrc = 768; k32l = 3; b0 = 512; ih = true; }
    else if (b < 704) { src = Wif; dst = pi + 196608; Nsrc = 768; k32l = 3; b0 = 608; ih = true; }
    else if (b < 832) { src = Wao; dst = pao;         Nsrc = 256; k32l = 5; b0 = 704; }
    else              { src = Wo;  dst = po;          Nsrc = 942; k32l = 3; b0 = 832; }
    int t8   = (b - b0) * 256 + threadIdx.x;
    int lane = t8 & 63;
    int K32  = 1 << k32l;
    int K    = K32 << 5;
    int ks   = (t8 >> 6) & (K32 - 1);
    int nt   = t8 >> (6 + k32l);
    int n    = nt * 16 + (lane & 15);
    int k0   = ks * 32 + ((lane >> 4) << 3);
    bf16x8 o;
    if (n < Nsrc) {
        const float* sp = src + (size_t)n * K + k0;
        float4 v0 = *(const float4*)sp;
        float4 v1 = *(const float4*)(sp + 4);
        float s = ih ? ((n < 512) ? NEG_L2E : TWO_L2E) : 1.f;
        o[0]=(__bf16)(v0.x*s); o[1]=(__bf16)(v0.y*s); o[2]=(__bf16)(v0.z*s); o[3]=(__bf16)(v0.w*s);
        o[4]=(__bf16)(v1.x*s); o[5]=(__bf16)(v1.y*s); o[6]=(__bf16)(v1.z*s); o[7]=(__bf16)(v1.w*s);
    } else {
#pragma unroll
        for (int q = 0; q < 8; q++) o[q] = (__bf16)0.f;
    }
    *(bf16x8*)(dst + (size_t)t8 * 8) = o;
}

// ---------------- barrier-free direct-frag MFMA GEMM ----------------
// C[M x N] = A[M x K] @ W^T (+bias), A bf16 row-major, W pre-packed frags.
// M=32 tiles: wave w = row-tile (w&1), col-half (w>>1). No LDS, no barriers: each lane's
// A-frag is 16 contiguous bytes A[mb*32+wrow*16+c][kb*64+kk*32+quad*8]; a wave's 64 lanes
// touch 16 rows x 64B = 16 full cache lines. #pragma unroll lets the compiler hoist the
// next iteration's loads over the current MFMAs (no barriers -> free scheduling).
// MODE 0: bf16 row-major. MODE 1: fp32 sigmoid masked to NREAL.
template<int MODE, int KDIM, int NTILES, int CSTRIDE, int NREAL>
__global__ __launch_bounds__(256) void gemm_k(
    const __bf16* __restrict__ Ap, const __bf16* __restrict__ Bp, void* __restrict__ Cp,
    const float* __restrict__ bias)
{
    const int tid = threadIdx.x;
    const int w = tid >> 6, lane = tid & 63, c = lane & 15, quad = lane >> 4;
    const int mb = blockIdx.x, nb = blockIdx.y;
    constexpr int K32 = KDIM / 32;
    constexpr int NK  = KDIM / 64;
    constexpr int NT_W = NTILES / 2;
    const int wrow = w & 1, ncol0 = (w >> 1) * NT_W;

    f32x4 acc[NT_W];
#pragma unroll
    for (int nt = 0; nt < NT_W; nt++) acc[nt] = (f32x4){0.f, 0.f, 0.f, 0.f};

    const __bf16* Arow = Ap + (size_t)(mb * 32 + wrow * 16 + c) * KDIM + quad * 8;
    const __bf16* Bbase = Bp + (size_t)((nb * NTILES + ncol0) * K32) * 512 + (size_t)lane * 8;

#pragma unroll 4
    for (int kb = 0; kb < NK; kb++) {
#pragma unroll
        for (int kk = 0; kk < 2; kk++) {
            bf16x8 a = *(const bf16x8*)(Arow + kb * 64 + kk * 32);
#pragma unroll
            for (int nt = 0; nt < NT_W; nt++) {
                bf16x8 bf = *(const bf16x8*)(Bbase + ((size_t)nt * K32 + kb * 2 + kk) * 512);
                acc[nt] = __builtin_amdgcn_mfma_f32_16x16x32_bf16(a, bf, acc[nt], 0, 0, 0);
            }
        }
    }

#pragma unroll
    for (int nt = 0; nt < NT_W; nt++) {
        int n = nb * (NTILES * 16) + (ncol0 + nt) * 16 + c;
        float bv = (n < NREAL) ? bias[n] : 0.f;
#pragma unroll
        for (int r0 = 0; r0 < 4; r0++) {
            int m = mb * 32 + wrow * 16 + quad * 4 + r0;
            float v = acc[nt][r0] + bv;
            if constexpr (MODE == 0) ((__bf16*)Cp)[(size_t)m * CSTRIDE + n] = (__bf16)v;
            else { if (n < NREAL) ((float*)Cp)[(size_t)m * CSTRIDE + n] = sigf(v); }
        }
    }
}

// ---------------- GRU cell nonlinearity for 4 dims (one lane) ----------------
// Magic-fma quantize: fma(h,127,1.5*2^23) puts round-to-nearest-even int8(h*127) in the low
// byte; 3x v_perm packs the 4 low bytes.
__device__ __forceinline__ void gru_cell4(
    const int4v a0, const int4v a1, const int4v a2,
    const f32x4 sc0, const f32x4 sc1, const f32x4 sc2, const f32x4 bnv,
    const bf16x4 g0, const bf16x4 g1, const bf16x4 g2,
    float* hreg, int* pk, bf16x4* hb)
{
    float f[4];
#pragma unroll
    for (int r = 0; r < 4; r++) {
        float er = __builtin_amdgcn_exp2f(fmaf((float)a0[r], sc0[r], (float)g0[r]));
        float rg = __builtin_amdgcn_rcpf(1.f + er);
        float ez = __builtin_amdgcn_exp2f(fmaf((float)a1[r], sc1[r], (float)g1[r]));
        float zg = __builtin_amdgcn_rcpf(1.f + ez);
        float narg = fmaf(rg, fmaf((float)a2[r], sc2[r], bnv[r]), (float)g2[r]);
        float en = __builtin_amdgcn_exp2f(narg);
        float ng = fmaf(-2.f, __builtin_amdgcn_rcpf(1.f + en), 1.f);
        float h  = fmaf(zg, hreg[r] - ng, ng);
        hreg[r] = h;
        (*hb)[r] = (__bf16)h;
        f[r] = fmaf(h, 127.f, 12582912.f);     // 1.5*2^23: low byte = RNE int8 two's complement
    }
    unsigned lo = __builtin_amdgcn_perm(__float_as_uint(f[1]), __float_as_uint(f[0]), 0x00000400u);
    unsigned hi = __builtin_amdgcn_perm(__float_as_uint(f[3]), __float_as_uint(f[2]), 0x04000000u);
    *pk = (int)__builtin_amdgcn_perm(hi, lo, 0x07060100u);
}

// ---------------- recurrent GRU (8 waves x 32 dims, frag-linear LDS) ----------------
// grid = 130 x 512. bid 0/1: forward halves; bid 2..129: reverse, longest-first.
// Wave w owns dims [32w, 32w+32): m-tiles (g*16 + 2w, g*16 + 2w + 1) per gate g.
// Per step: 4x ds_read_b128 (each wave reads full h once) -> 24 MFMA (3 gates x 2 tiles x
// 4 ks, weights 96 regs) -> nonlin for 8 dims/lane (2x gru_cell4) -> 2x b32 LDS write ->
// gate reload (same regs, post-use pre-store) -> 2x b64 global store -> lgkm barrier.
// h LDS frag-linear: byte = buf*4096 + (d>>6)*1024 + (batch | (((d>>4)&3)<<4))*16 + (d&15).
__global__ __launch_bounds__(512, 2) void gru_recurrent(
    const signed char* __restrict__ wq, const float* __restrict__ wscale,
    const float* __restrict__ bhh_r, const float* __restrict__ bhh_f,
    const __bf16* __restrict__ Gi,
    __bf16* __restrict__ revb, __bf16* __restrict__ fwdb)
{
    __shared__ __align__(16) signed char hbuf[2][4096];
    const int tid = threadIdx.x;
    const int w = tid >> 6, lane = tid & 63, c = lane & 15, quad = lane >> 4;
    const int bid = blockIdx.x;
    const bool isF = (bid < 2);
    const int ia = isF ? 63 : (63 - ((bid - 2) >> 1));
    const int b0 = (bid & 1) << 4;
    const int steps = ia + 1;
    const float* bhh = isF ? bhh_f : bhh_r;
    __bf16* outb = isF ? fwdb : (revb + ((size_t)(ia * (ia + 1) / 2)) * 8192);
    const int dirb = isF ? 768 : 0;

    // Whh int8 A-frags: wave w owns m-tiles (g*16 + 2w + mt), 24 frags = 96 regs
    const int4v* pw = (const int4v*)(wq + (isF ? 196608 : 0));
    int4v bw[3][2][4];
#pragma unroll
    for (int g = 0; g < 3; g++)
#pragma unroll
        for (int mt = 0; mt < 2; mt++)
#pragma unroll
            for (int ks = 0; ks < 4; ks++)
                bw[g][mt][ks] = pw[(size_t)((g * 16 + 2 * w + mt) * 4 + ks) * 64 + lane];

    const int d0 = (w << 5) + (quad << 2);   // tile 2w:   dims d0..d0+3 of batch c
    const int d1 = d0 + 16;                  // tile 2w+1: dims d1..d1+3 of batch c
    f32x4 sc[3][2], bnv[2];
#pragma unroll
    for (int g = 0; g < 3; g++)
#pragma unroll
        for (int mt = 0; mt < 2; mt++)
            sc[g][mt] = *(const f32x4*)&wscale[dirb + g * 256 + d0 + 16 * mt];
#pragma unroll
    for (int mt = 0; mt < 2; mt++) {
        bnv[mt] = *(const f32x4*)&bhh[512 + d0 + 16 * mt];
#pragma unroll
        for (int q = 0; q < 4; q++) bnv[mt][q] *= TWO_L2E;
    }

    float hreg[8] = {0.f, 0.f, 0.f, 0.f, 0.f, 0.f, 0.f, 0.f};
    ((int*)hbuf)[tid]        = 0; ((int*)hbuf)[tid + 512]  = 0;
    ((int*)hbuf)[tid + 1024] = 0; ((int*)hbuf)[tid + 1536] = 0;
    __syncthreads();

    // Gi row-major [t*32+b][1536]: lane reads 8B per (gate, tile) at its (batch,dim) spot
    const __bf16* grow = Gi + (size_t)((isF ? 0 : ia) * 32 + b0 + c) * 1536 + dirb;
    const long gstep = isF ? (32 * 1536) : -(32 * 1536);
    __bf16* go = outb + (size_t)(b0 + c) * 256 + d0;

    // frag-linear LDS offsets
    const int wr0 = ((d0 >> 6) << 10) + ((c | (((d0 >> 4) & 3) << 4)) << 4) + (d0 & 15);
    const int wr1 = ((d1 >> 6) << 10) + ((c | (((d1 >> 4) & 3) << 4)) << 4) + (d1 & 15);
    const int rd_off = lane << 4;

    bf16x4 gc[3][2];
#pragma unroll
    for (int g = 0; g < 3; g++)
#pragma unroll
        for (int mt = 0; mt < 2; mt++)
            gc[g][mt] = *(const bf16x4*)(grow + g * 256 + d0 + 16 * mt);

    for (int j = 0; j < steps; j++) {
        const int rb = j & 1, wbuf = rb ^ 1;
        const bool more = (j + 1 < steps);

        int4v acc[3][2];
#pragma unroll
        for (int g = 0; g < 3; g++)
#pragma unroll
            for (int mt = 0; mt < 2; mt++) acc[g][mt] = (int4v){0, 0, 0, 0};
#pragma unroll
        for (int ks = 0; ks < 4; ks++) {
            int4v av = *(const int4v*)&hbuf[rb][ks * 1024 + rd_off];  // full h B-frag
#pragma unroll
            for (int g = 0; g < 3; g++) {
                acc[g][0] = __builtin_amdgcn_mfma_i32_16x16x64_i8(bw[g][0][ks], av, acc[g][0], 0, 0, 0);
                acc[g][1] = __builtin_amdgcn_mfma_i32_16x16x64_i8(bw[g][1][ks], av, acc[g][1], 0, 0, 0);
            }
        }

        int pk0, pk1; bf16x4 hb0, hb1;
        gru_cell4(acc[0][0], acc[1][0], acc[2][0], sc[0][0], sc[1][0], sc[2][0], bnv[0],
                  gc[0][0], gc[1][0], gc[2][0], &hreg[0], &pk0, &hb0);
        gru_cell4(acc[0][1], acc[1][1], acc[2][1], sc[0][1], sc[1][1], sc[2][1], bnv[1],
                  gc[0][1], gc[1][1], gc[2][1], &hreg[4], &pk1, &hb1);

        *(int*)&hbuf[wbuf][wr0] = pk0;     // 2-way banks (4c+quad): free
        *(int*)&hbuf[wbuf][wr1] = pk1;

        if (more) {    // reload gates into the SAME regs (post-use, pre-store: no store drain)
            grow += gstep;
#pragma unroll
            for (int g = 0; g < 3; g++)
#pragma unroll
                for (int mt = 0; mt < 2; mt++)
                    gc[g][mt] = *(const bf16x4*)(grow + g * 256 + d0 + 16 * mt);
        }

        *(bf16x4*)go = hb0;                // fire-and-forget global stores
        *(bf16x4*)(go + 16) = hb1;
        go += 8192;
        LDS_BARRIER();
    }
}

// ---------------- attention (online softmax over t<=i) ----------------
__global__ __launch_bounds__(512) void attn_kernel(
    const __bf16* __restrict__ revb, const __bf16* __restrict__ fwdb,
    const float* __restrict__ attn_w, const float* __restrict__ attn_bp,
    __bf16* __restrict__ ht)
{
    const int tid = threadIdx.x;
    const int w = tid >> 6, lane = tid & 63;
    const int wid = blockIdx.x * 8 + w;      // 2048 waves: one per (i,b)
    const int i = wid >> 5, b = wid & 31;
    const int d0 = lane * 4;

    float wf[4], wr[4];
#pragma unroll
    for (int q = 0; q < 4; q++) { wf[q] = attn_w[d0 + q]; wr[q] = attn_w[256 + d0 + q]; }
    const float ab = attn_bp[0];
    const __bf16* rp = revb + ((size_t)(i * (i + 1) / 2)) * 8192 + (size_t)b * 256 + d0;
    const __bf16* fp = fwdb + (size_t)b * 256 + d0;

    float mx = -1e30f, l = 0.f;
    float cf[4] = {0,0,0,0}, cr[4] = {0,0,0,0};
    bf16x4 rn = *(const bf16x4*)rp, fn = *(const bf16x4*)fp;
    for (int t = 0; t <= i; t++) {
        bf16x4 rv4 = rn, fv4 = fn;
        if (t < i) {
            rn = *(const bf16x4*)(rp + (size_t)(t + 1) * 8192);
            fn = *(const bf16x4*)(fp + (size_t)(t + 1) * 8192);
        }
        float rv[4], fv[4], s = 0.f;
#pragma unroll
        for (int q = 0; q < 4; q++) {
            rv[q] = (float)rv4[q]; fv[q] = (float)fv4[q];
            s += rv[q] * wr[q] + fv[q] * wf[q];
        }
#pragma unroll
        for (int off = 32; off > 0; off >>= 1) s += __shfl_xor(s, off);
        s += ab;
        float mn = fmaxf(mx, s);
        float scl = __expf(mx - mn);
        float p  = __expf(s - mn);
        l = l * scl + p;
#pragma unroll
        for (int q = 0; q < 4; q++) { cf[q] = cf[q] * scl + p * fv[q]; cr[q] = cr[q] * scl + p * rv[q]; }
        mx = mn;
    }
    float inv = __builtin_amdgcn_rcpf(l * (float)(i + 1));
    __bf16* hp = ht + (size_t)(i * 32 + b) * 1024 + d0;
    const __bf16* fl = fp + (size_t)i * 8192;
    const __bf16* rl = rp + (size_t)i * 8192;
#pragma unroll
    for (int q = 0; q < 4; q++) {
        hp[q]       = (__bf16)(cf[q] * inv);
        hp[256 + q] = (__bf16)(cr[q] * inv);
        hp[512 + q] = fl[q];
        hp[768 + q] = rl[q];
    }
}

// ---------------- launch ----------------
extern "C" void kernel_launch(void* const* d_in, const int* in_sizes, int n_in,
                              void* d_out, int out_size, void* d_ws, size_t ws_size,
                              hipStream_t stream) {
    const float* x      = (const float*)d_in[0];
    const float* W_emb  = (const float*)d_in[1];
    const float* b_emb  = (const float*)d_in[2];
    const float* Wih_f  = (const float*)d_in[3];
    const float* Whh_f  = (const float*)d_in[4];
    const float* bih_f  = (const float*)d_in[5];
    const float* bhh_f  = (const float*)d_in[6];
    const float* Wih_r  = (const float*)d_in[7];
    const float* Whh_r  = (const float*)d_in[8];
    const float* bih_r  = (const float*)d_in[9];
    const float* bhh_r  = (const float*)d_in[10];
    const float* attn_w = (const float*)d_in[11];
    const float* attn_b = (const float*)d_in[12];
    const float* W_ao   = (const float*)d_in[13];
    const float* b_ao   = (const float*)d_in[14];
    const float* W_o    = (const float*)d_in[15];
    const float* b_o    = (const float*)d_in[16];
    float* out = (float*)d_out;

    char* ws = (char*)d_ws;
    __bf16* pk_emb = (__bf16*)(ws + OFF_PK_EMB);
    __bf16* pk_ih  = (__bf16*)(ws + OFF_PK_IH);
    signed char* wq = (signed char*)(ws + OFF_WQ);
    float*  wsc    = (float*)(ws + OFF_WSC);
    __bf16* pk_ao  = (__bf16*)(ws + OFF_PK_AO);
    __bf16* pk_o   = (__bf16*)(ws + OFF_PK_O);
    __bf16* day    = (__bf16*)(ws + OFF_DAY);
    __bf16* Gi     = (__bf16*)(ws + OFF_GIT);
    float*  bc     = (float*)(ws + OFF_BC);
    __bf16* revb   = (__bf16*)(ws + OFF_REV);
    __bf16* fwdb   = (__bf16*)(ws + OFF_FWD);
    __bf16* ht     = (__bf16*)(ws + OFF_HT);
    __bf16* tmp1   = (__bf16*)(ws + OFF_TMP1);
    __bf16* xb     = (__bf16*)(ws + OFF_XB);     // aliases revb (dead until gru)

    pack_misc<<<5432, 256, 0, stream>>>(W_emb, Wih_r, Wih_f, W_ao, W_o, x,
                                        Whh_r, Whh_f, bih_r, bih_f, bhh_r, bhh_f,
                                        pk_emb, pk_ih, pk_ao, pk_o, xb, wq, wsc, bc);

    gemm_k<0, 4096, 4, 256, 256><<<dim3(64, 4), 256, 0, stream>>>(xb, pk_emb, day, b_emb);
    gemm_k<0, 256, 4, 1536, 1536><<<dim3(64, 24), 256, 0, stream>>>(day, pk_ih, Gi, bc);

    gru_recurrent<<<130, 512, 0, stream>>>(wq, wsc, bhh_r, bhh_f, Gi, revb, fwdb);

    attn_kernel<<<256, 512, 0, stream>>>(revb, fwdb, attn_w, attn_b, ht);

    gemm_k<0, 1024, 4, 256, 256><<<dim3(64, 4), 256, 0, stream>>>(ht, pk_ao, tmp1, b_ao);
    gemm_k<1, 256, 4, 942, 942><<<dim3(64, 15), 256, 0, stream>>>(tmp1, pk_o, out, b_o);
}

// Round 6
// 307.390 us; speedup vs baseline: 1.1137x; 1.1137x over previous
//
#include <hip/hip_runtime.h>
#include <hip/hip_bf16.h>

// Dipole: day-emb GEMM -> fwd GRU + 64 reverse GRUs -> masked softmax attention -> 2-layer head.
// T=64 B=32 D_IN=4096 D_DAY=H=256 D_OUT=942.
//
//  k4 gru_recurrent : 8-wave R3 version (118us, near phase-serial bound -- parked).
//  gemm_k           : EXACT R3 staged version (best measured: non-GRU 191us). R4 (depth-2)
//                     and R5 (barrier-free direct-frag) both regressed -- in-order vmcnt
//                     means neither added hidden slack; R3's 2-barrier staged loop stands.
//  R6 change        : occupancy only. day gemm (K=4096) and ao gemm (K=1024) ran grid
//                     (64,4) = 256 blocks = 1 block/CU = 1 wave/SIMD -- latency-bound with
//                     zero TLP. Column-split NTILES 4->2, grid.y 4->8 = 2 blocks/CU; the
//                     second block fills the first's barrier/load stalls. Template code
//                     unchanged; per-element accumulation order unchanged.

typedef __bf16 bf16x8 __attribute__((ext_vector_type(8)));
typedef __bf16 bf16x4 __attribute__((ext_vector_type(4)));
typedef float  f32x4  __attribute__((ext_vector_type(4)));
typedef int    int4v  __attribute__((ext_vector_type(4)));

static constexpr float NEG_L2E = -1.442695041f;   // -log2(e)
static constexpr float TWO_L2E =  2.885390082f;   //  2*log2(e)

// ---------------- workspace layout (bytes) ----------------
static constexpr size_t OFF_PK_EMB = 0;                        // 256x4096 bf16    = 2097152
static constexpr size_t OFF_PK_IH  = 2097152;                  // 1536x256 bf16    =  786432
static constexpr size_t OFF_WQ     = 2883584;                  // 2x768x256 int8   =  393216
static constexpr size_t OFF_WSC    = 3276800;                  // 1536 f32         =    6144
static constexpr size_t OFF_PK_AO  = 3670016;                  // 256x1024 bf16    =  524288
static constexpr size_t OFF_PK_O   = 4194304;                  // 960x256 bf16     =  491520
static constexpr size_t OFF_DAY    = 4685824;                  // 2048x256 bf16    = 1048576
static constexpr size_t OFF_GIT    = 5734400;                  // 2048x1536 bf16   = 6291456
static constexpr size_t OFF_BC     = 12025856;                 // 1536 f32         =    6144
static constexpr size_t OFF_REV    = 18317312;                 // 2080*32*256 bf16 = 34078720
static constexpr size_t OFF_FWD    = 52396032;                 // 64*32*256 bf16   = 1048576
static constexpr size_t OFF_HT     = 53444608;                 // 2048x1024 bf16   = 4194304
static constexpr size_t OFF_TMP1   = 57638912;                 // 2048x256 bf16    = 1048576
// xb (2048x4096 bf16 = 16.7MB) aliases OFF_REV: dead before gru_recurrent writes rev.
static constexpr size_t OFF_XB     = OFF_REV;

__device__ __forceinline__ float sigf(float x) {
    return __builtin_amdgcn_rcpf(1.f + __expf(-x));
}

// lgkmcnt-only barrier: does NOT drain vmcnt.
#define LDS_BARRIER() asm volatile("s_waitcnt lgkmcnt(0)\n\ts_barrier" ::: "memory")

// ---------------- fused packer: bf16 frags + x->bf16 + Whh int8 + bias ----------------
// bf16 frag layout: flat = ((nt*K32+ks)*64+lane)*8+j holds W[nt*16+lane%16][ks*32+(lane/16)*8+j]
// i8 frag (A/B lane-symmetric): (n,k): lane=(n&15)|(((k>>4)&3)<<4), byte j=k&15;
//   flat = dir*196608 + ((n>>4)*4 + (k>>6))*1024 + lane*16 + j.
__global__ __launch_bounds__(256) void pack_misc(
    const float* __restrict__ We,  const float* __restrict__ Wir, const float* __restrict__ Wif,
    const float* __restrict__ Wao, const float* __restrict__ Wo,  const float* __restrict__ x,
    const float* __restrict__ Whr, const float* __restrict__ Whf,
    const float* __restrict__ bih_r, const float* __restrict__ bih_f,
    const float* __restrict__ bhh_r, const float* __restrict__ bhh_f,
    __bf16* pe, __bf16* pi, __bf16* pao, __bf16* po, __bf16* xb,
    signed char* __restrict__ wq, float* __restrict__ wscale, float* __restrict__ bc)
{
    int b = blockIdx.x;
    if (b >= 5048) {                      // Whh int8 pack: 4 rows per block (one per wave)
        int rowb = (b - 5048) * 4 + (threadIdx.x >> 6);   // 0..1535: dir*768 + n
        int t = threadIdx.x & 63;
        int dir = (rowb >= 768) ? 1 : 0;
        int n = rowb - dir * 768;
        const float* src = (dir ? Whf : Whr) + (size_t)n * 256;
        float4 wv = ((const float4*)src)[t];
        float m = fmaxf(fmaxf(fabsf(wv.x), fabsf(wv.y)), fmaxf(fabsf(wv.z), fabsf(wv.w)));
#pragma unroll
        for (int off = 32; off > 0; off >>= 1) m = fmaxf(m, __shfl_xor(m, off));
        m = fmaxf(m, 1e-20f);
        float inv = 127.f / m;
        int q0 = (int)__builtin_rintf(wv.x * inv);
        int q1 = (int)__builtin_rintf(wv.y * inv);
        int q2 = (int)__builtin_rintf(wv.z * inv);
        int q3 = (int)__builtin_rintf(wv.w * inv);
        int pk = (q0 & 0xff) | ((q1 & 0xff) << 8) | ((q2 & 0xff) << 16) | ((q3 & 0xff) << 24);
        int dlane = (n & 15) | (((t >> 2) & 3) << 4);
        size_t byte = (size_t)dir * 196608 + ((size_t)(n >> 4) * 4 + (t >> 4)) * 1024
                    + (size_t)dlane * 16 + (t & 3) * 4;
        *(int*)(wq + byte) = pk;
        if (t == 0) {
            float gc = (n < 512) ? NEG_L2E : TWO_L2E;
            wscale[rowb] = m * (1.f / 16129.f) * gc;
            const float* bi = dir ? bih_f : bih_r;
            const float* bh = dir ? bhh_f : bhh_r;
            bc[rowb] = (n < 512) ? (bi[n] + bh[n]) * NEG_L2E : bi[n] * TWO_L2E;
        }
        return;
    }
    if (b >= 952) {                       // x -> bf16 (8 elems/thread)
        size_t base = ((size_t)(b - 952) * 256 + threadIdx.x) * 8;
        float4 v0 = *(const float4*)(x + base);
        float4 v1 = *(const float4*)(x + base + 4);
        bf16x8 o;
        o[0]=(__bf16)v0.x; o[1]=(__bf16)v0.y; o[2]=(__bf16)v0.z; o[3]=(__bf16)v0.w;
        o[4]=(__bf16)v1.x; o[5]=(__bf16)v1.y; o[6]=(__bf16)v1.z; o[7]=(__bf16)v1.w;
        *(bf16x8*)(xb + base) = o;
        return;
    }
    const float* src; __bf16* dst; int Nsrc, k32l, b0; bool ih = false;
    if (b < 512)      { src = We;  dst = pe;          Nsrc = 256; k32l = 7; b0 = 0;   }
    else if (b < 608) { src = Wir; dst = pi;          Nsrc = 768; k32l = 3; b0 = 512; ih = true; }
    else if (b < 704) { src = Wif; dst = pi + 196608; Nsrc = 768; k32l = 3; b0 = 608; ih = true; }
    else if (b < 832) { src = Wao; dst = pao;         Nsrc = 256; k32l = 5; b0 = 704; }
    else              { src = Wo;  dst = po;          Nsrc = 942; k32l = 3; b0 = 832; }
    int t8   = (b - b0) * 256 + threadIdx.x;
    int lane = t8 & 63;
    int K32  = 1 << k32l;
    int K    = K32 << 5;
    int ks   = (t8 >> 6) & (K32 - 1);
    int nt   = t8 >> (6 + k32l);
    int n    = nt * 16 + (lane & 15);
    int k0   = ks * 32 + ((lane >> 4) << 3);
    bf16x8 o;
    if (n < Nsrc) {
        const float* sp = src + (size_t)n * K + k0;
        float4 v0 = *(const float4*)sp;
        float4 v1 = *(const float4*)(sp + 4);
        float s = ih ? ((n < 512) ? NEG_L2E : TWO_L2E) : 1.f;
        o[0]=(__bf16)(v0.x*s); o[1]=(__bf16)(v0.y*s); o[2]=(__bf16)(v0.z*s); o[3]=(__bf16)(v0.w*s);
        o[4]=(__bf16)(v1.x*s); o[5]=(__bf16)(v1.y*s); o[6]=(__bf16)(v1.z*s); o[7]=(__bf16)(v1.w*s);
    } else {
#pragma unroll
        for (int q = 0; q < 8; q++) o[q] = (__bf16)0.f;
    }
    *(bf16x8*)(dst + (size_t)t8 * 8) = o;
}

// ---------------- generic MFMA GEMM: C[M x N] = A[M x K] @ W^T (+bias), A bf16 ----------------
// EXACT R3 version (best measured). M=32 tiles: wave w = row-tile (w&1), col-half (w>>1).
// Register double-buffer of B-frags. MODE 0: bf16 row-major. MODE 1: fp32 sigmoid to NREAL.
template<int MODE, int KDIM, int NTILES, int CSTRIDE, int NREAL>
__global__ __launch_bounds__(256) void gemm_k(
    const __bf16* __restrict__ Ap, const __bf16* __restrict__ Bp, void* __restrict__ Cp,
    const float* __restrict__ bias)
{
    __shared__ __align__(16) __bf16 As[32][88];
    const int tid = threadIdx.x;
    const int w = tid >> 6, lane = tid & 63, c = lane & 15, quad = lane >> 4;
    const int mb = blockIdx.x, nb = blockIdx.y;
    constexpr int K32 = KDIM / 32;
    constexpr int NK  = KDIM / 64;
    constexpr int NT_W = NTILES / 2;
    const int wrow = w & 1, ncol0 = (w >> 1) * NT_W;

    f32x4 acc[NT_W];
#pragma unroll
    for (int nt = 0; nt < NT_W; nt++) acc[nt] = (f32x4){0.f, 0.f, 0.f, 0.f};

    const int row = tid >> 3, kp = (tid & 7) * 8;
    uint4 pb;
    auto issue  = [&](int kb) { pb = *(const uint4*)(Ap + (size_t)(mb * 32 + row) * KDIM + kb * 64 + kp); };
    auto commit = [&]() { *(uint4*)&As[row][kp] = pb; };

    bf16x8 bcur[2][NT_W], bnxt[2][NT_W];
    auto loadB = [&](int kb, bf16x8 (&dst)[2][NT_W]) {
#pragma unroll
        for (int kk = 0; kk < 2; kk++)
#pragma unroll
            for (int nt = 0; nt < NT_W; nt++)
                dst[kk][nt] = *(const bf16x8*)(Bp +
                    ((size_t)((nb * NTILES + ncol0 + nt) * K32 + kb * 2 + kk) * 64 + lane) * 8);
    };

    issue(0);
    loadB(0, bcur);
    for (int kb = 0; kb < NK; kb++) {
        commit();
        __syncthreads();
        if (kb + 1 < NK) { issue(kb + 1); loadB(kb + 1, bnxt); }
#pragma unroll
        for (int kk = 0; kk < 2; kk++) {
            bf16x8 a = *(const bf16x8*)&As[wrow * 16 + c][kk * 32 + quad * 8];
#pragma unroll
            for (int nt = 0; nt < NT_W; nt++)
                acc[nt] = __builtin_amdgcn_mfma_f32_16x16x32_bf16(a, bcur[kk][nt], acc[nt], 0, 0, 0);
        }
        if (kb + 1 < NK) {
#pragma unroll
            for (int kk = 0; kk < 2; kk++)
#pragma unroll
                for (int nt = 0; nt < NT_W; nt++) bcur[kk][nt] = bnxt[kk][nt];
        }
        __syncthreads();
    }

#pragma unroll
    for (int nt = 0; nt < NT_W; nt++) {
        int n = nb * (NTILES * 16) + (ncol0 + nt) * 16 + c;
        float bv = (n < NREAL) ? bias[n] : 0.f;
#pragma unroll
        for (int r0 = 0; r0 < 4; r0++) {
            int m = mb * 32 + wrow * 16 + quad * 4 + r0;
            float v = acc[nt][r0] + bv;
            if constexpr (MODE == 0) ((__bf16*)Cp)[(size_t)m * CSTRIDE + n] = (__bf16)v;
            else { if (n < NREAL) ((float*)Cp)[(size_t)m * CSTRIDE + n] = sigf(v); }
        }
    }
}

// ---------------- GRU cell nonlinearity for 4 dims (one lane) ----------------
// Magic-fma quantize: fma(h,127,1.5*2^23) puts round-to-nearest-even int8(h*127) in the low
// byte; 3x v_perm packs the 4 low bytes.
__device__ __forceinline__ void gru_cell4(
    const int4v a0, const int4v a1, const int4v a2,
    const f32x4 sc0, const f32x4 sc1, const f32x4 sc2, const f32x4 bnv,
    const bf16x4 g0, const bf16x4 g1, const bf16x4 g2,
    float* hreg, int* pk, bf16x4* hb)
{
    float f[4];
#pragma unroll
    for (int r = 0; r < 4; r++) {
        float er = __builtin_amdgcn_exp2f(fmaf((float)a0[r], sc0[r], (float)g0[r]));
        float rg = __builtin_amdgcn_rcpf(1.f + er);
        float ez = __builtin_amdgcn_exp2f(fmaf((float)a1[r], sc1[r], (float)g1[r]));
        float zg = __builtin_amdgcn_rcpf(1.f + ez);
        float narg = fmaf(rg, fmaf((float)a2[r], sc2[r], bnv[r]), (float)g2[r]);
        float en = __builtin_amdgcn_exp2f(narg);
        float ng = fmaf(-2.f, __builtin_amdgcn_rcpf(1.f + en), 1.f);
        float h  = fmaf(zg, hreg[r] - ng, ng);
        hreg[r] = h;
        (*hb)[r] = (__bf16)h;
        f[r] = fmaf(h, 127.f, 12582912.f);     // 1.5*2^23: low byte = RNE int8 two's complement
    }
    unsigned lo = __builtin_amdgcn_perm(__float_as_uint(f[1]), __float_as_uint(f[0]), 0x00000400u);
    unsigned hi = __builtin_amdgcn_perm(__float_as_uint(f[3]), __float_as_uint(f[2]), 0x04000000u);
    *pk = (int)__builtin_amdgcn_perm(hi, lo, 0x07060100u);
}

// ---------------- recurrent GRU (8 waves x 32 dims, frag-linear LDS) ----------------
// grid = 130 x 512. bid 0/1: forward halves; bid 2..129: reverse, longest-first.
// Wave w owns dims [32w, 32w+32): m-tiles (g*16 + 2w, g*16 + 2w + 1) per gate g.
// Per step: 4x ds_read_b128 (each wave reads full h once) -> 24 MFMA (3 gates x 2 tiles x
// 4 ks, weights 96 regs) -> nonlin for 8 dims/lane (2x gru_cell4) -> 2x b32 LDS write ->
// gate reload (same regs, post-use pre-store) -> 2x b64 global store -> lgkm barrier.
// h LDS frag-linear: byte = buf*4096 + (d>>6)*1024 + (batch | (((d>>4)&3)<<4))*16 + (d&15).
__global__ __launch_bounds__(512, 2) void gru_recurrent(
    const signed char* __restrict__ wq, const float* __restrict__ wscale,
    const float* __restrict__ bhh_r, const float* __restrict__ bhh_f,
    const __bf16* __restrict__ Gi,
    __bf16* __restrict__ revb, __bf16* __restrict__ fwdb)
{
    __shared__ __align__(16) signed char hbuf[2][4096];
    const int tid = threadIdx.x;
    const int w = tid >> 6, lane = tid & 63, c = lane & 15, quad = lane >> 4;
    const int bid = blockIdx.x;
    const bool isF = (bid < 2);
    const int ia = isF ? 63 : (63 - ((bid - 2) >> 1));
    const int b0 = (bid & 1) << 4;
    const int steps = ia + 1;
    const float* bhh = isF ? bhh_f : bhh_r;
    __bf16* outb = isF ? fwdb : (revb + ((size_t)(ia * (ia + 1) / 2)) * 8192);
    const int dirb = isF ? 768 : 0;

    // Whh int8 A-frags: wave w owns m-tiles (g*16 + 2w + mt), 24 frags = 96 regs
    const int4v* pw = (const int4v*)(wq + (isF ? 196608 : 0));
    int4v bw[3][2][4];
#pragma unroll
    for (int g = 0; g < 3; g++)
#pragma unroll
        for (int mt = 0; mt < 2; mt++)
#pragma unroll
            for (int ks = 0; ks < 4; ks++)
                bw[g][mt][ks] = pw[(size_t)((g * 16 + 2 * w + mt) * 4 + ks) * 64 + lane];

    const int d0 = (w << 5) + (quad << 2);   // tile 2w:   dims d0..d0+3 of batch c
    const int d1 = d0 + 16;                  // tile 2w+1: dims d1..d1+3 of batch c
    f32x4 sc[3][2], bnv[2];
#pragma unroll
    for (int g = 0; g < 3; g++)
#pragma unroll
        for (int mt = 0; mt < 2; mt++)
            sc[g][mt] = *(const f32x4*)&wscale[dirb + g * 256 + d0 + 16 * mt];
#pragma unroll
    for (int mt = 0; mt < 2; mt++) {
        bnv[mt] = *(const f32x4*)&bhh[512 + d0 + 16 * mt];
#pragma unroll
        for (int q = 0; q < 4; q++) bnv[mt][q] *= TWO_L2E;
    }

    float hreg[8] = {0.f, 0.f, 0.f, 0.f, 0.f, 0.f, 0.f, 0.f};
    ((int*)hbuf)[tid]        = 0; ((int*)hbuf)[tid + 512]  = 0;
    ((int*)hbuf)[tid + 1024] = 0; ((int*)hbuf)[tid + 1536] = 0;
    __syncthreads();

    // Gi row-major [t*32+b][1536]: lane reads 8B per (gate, tile) at its (batch,dim) spot
    const __bf16* grow = Gi + (size_t)((isF ? 0 : ia) * 32 + b0 + c) * 1536 + dirb;
    const long gstep = isF ? (32 * 1536) : -(32 * 1536);
    __bf16* go = outb + (size_t)(b0 + c) * 256 + d0;

    // frag-linear LDS offsets
    const int wr0 = ((d0 >> 6) << 10) + ((c | (((d0 >> 4) & 3) << 4)) << 4) + (d0 & 15);
    const int wr1 = ((d1 >> 6) << 10) + ((c | (((d1 >> 4) & 3) << 4)) << 4) + (d1 & 15);
    const int rd_off = lane << 4;

    bf16x4 gc[3][2];
#pragma unroll
    for (int g = 0; g < 3; g++)
#pragma unroll
        for (int mt = 0; mt < 2; mt++)
            gc[g][mt] = *(const bf16x4*)(grow + g * 256 + d0 + 16 * mt);

    for (int j = 0; j < steps; j++) {
        const int rb = j & 1, wbuf = rb ^ 1;
        const bool more = (j + 1 < steps);

        int4v acc[3][2];
#pragma unroll
        for (int g = 0; g < 3; g++)
#pragma unroll
            for (int mt = 0; mt < 2; mt++) acc[g][mt] = (int4v){0, 0, 0, 0};
#pragma unroll
        for (int ks = 0; ks < 4; ks++) {
            int4v av = *(const int4v*)&hbuf[rb][ks * 1024 + rd_off];  // full h B-frag
#pragma unroll
            for (int g = 0; g < 3; g++) {
                acc[g][0] = __builtin_amdgcn_mfma_i32_16x16x64_i8(bw[g][0][ks], av, acc[g][0], 0, 0, 0);
                acc[g][1] = __builtin_amdgcn_mfma_i32_16x16x64_i8(bw[g][1][ks], av, acc[g][1], 0, 0, 0);
            }
        }

        int pk0, pk1; bf16x4 hb0, hb1;
        gru_cell4(acc[0][0], acc[1][0], acc[2][0], sc[0][0], sc[1][0], sc[2][0], bnv[0],
                  gc[0][0], gc[1][0], gc[2][0], &hreg[0], &pk0, &hb0);
        gru_cell4(acc[0][1], acc[1][1], acc[2][1], sc[0][1], sc[1][1], sc[2][1], bnv[1],
                  gc[0][1], gc[1][1], gc[2][1], &hreg[4], &pk1, &hb1);

        *(int*)&hbuf[wbuf][wr0] = pk0;     // 2-way banks (4c+quad): free
        *(int*)&hbuf[wbuf][wr1] = pk1;

        if (more) {    // reload gates into the SAME regs (post-use, pre-store: no store drain)
            grow += gstep;
#pragma unroll
            for (int g = 0; g < 3; g++)
#pragma unroll
                for (int mt = 0; mt < 2; mt++)
                    gc[g][mt] = *(const bf16x4*)(grow + g * 256 + d0 + 16 * mt);
        }

        *(bf16x4*)go = hb0;                // fire-and-forget global stores
        *(bf16x4*)(go + 16) = hb1;
        go += 8192;
        LDS_BARRIER();
    }
}

// ---------------- attention (online softmax over t<=i) ----------------
__global__ __launch_bounds__(512) void attn_kernel(
    const __bf16* __restrict__ revb, const __bf16* __restrict__ fwdb,
    const float* __restrict__ attn_w, const float* __restrict__ attn_bp,
    __bf16* __restrict__ ht)
{
    const int tid = threadIdx.x;
    const int w = tid >> 6, lane = tid & 63;
    const int wid = blockIdx.x * 8 + w;      // 2048 waves: one per (i,b)
    const int i = wid >> 5, b = wid & 31;
    const int d0 = lane * 4;

    float wf[4], wr[4];
#pragma unroll
    for (int q = 0; q < 4; q++) { wf[q] = attn_w[d0 + q]; wr[q] = attn_w[256 + d0 + q]; }
    const float ab = attn_bp[0];
    const __bf16* rp = revb + ((size_t)(i * (i + 1) / 2)) * 8192 + (size_t)b * 256 + d0;
    const __bf16* fp = fwdb + (size_t)b * 256 + d0;

    float mx = -1e30f, l = 0.f;
    float cf[4] = {0,0,0,0}, cr[4] = {0,0,0,0};
    bf16x4 rn = *(const bf16x4*)rp, fn = *(const bf16x4*)fp;
    for (int t = 0; t <= i; t++) {
        bf16x4 rv4 = rn, fv4 = fn;
        if (t < i) {
            rn = *(const bf16x4*)(rp + (size_t)(t + 1) * 8192);
            fn = *(const bf16x4*)(fp + (size_t)(t + 1) * 8192);
        }
        float rv[4], fv[4], s = 0.f;
#pragma unroll
        for (int q = 0; q < 4; q++) {
            rv[q] = (float)rv4[q]; fv[q] = (float)fv4[q];
            s += rv[q] * wr[q] + fv[q] * wf[q];
        }
#pragma unroll
        for (int off = 32; off > 0; off >>= 1) s += __shfl_xor(s, off);
        s += ab;
        float mn = fmaxf(mx, s);
        float scl = __expf(mx - mn);
        float p  = __expf(s - mn);
        l = l * scl + p;
#pragma unroll
        for (int q = 0; q < 4; q++) { cf[q] = cf[q] * scl + p * fv[q]; cr[q] = cr[q] * scl + p * rv[q]; }
        mx = mn;
    }
    float inv = __builtin_amdgcn_rcpf(l * (float)(i + 1));
    __bf16* hp = ht + (size_t)(i * 32 + b) * 1024 + d0;
    const __bf16* fl = fp + (size_t)i * 8192;
    const __bf16* rl = rp + (size_t)i * 8192;
#pragma unroll
    for (int q = 0; q < 4; q++) {
        hp[q]       = (__bf16)(cf[q] * inv);
        hp[256 + q] = (__bf16)(cr[q] * inv);
        hp[512 + q] = fl[q];
        hp[768 + q] = rl[q];
    }
}

// ---------------- launch ----------------
extern "C" void kernel_launch(void* const* d_in, const int* in_sizes, int n_in,
                              void* d_out, int out_size, void* d_ws, size_t ws_size,
                              hipStream_t stream) {
    const float* x      = (const float*)d_in[0];
    const float* W_emb  = (const float*)d_in[1];
    const float* b_emb  = (const float*)d_in[2];
    const float* Wih_f  = (const float*)d_in[3];
    const float* Whh_f  = (const float*)d_in[4];
    const float* bih_f  = (const float*)d_in[5];
    const float* bhh_f  = (const float*)d_in[6];
    const float* Wih_r  = (const float*)d_in[7];
    const float* Whh_r  = (const float*)d_in[8];
    const float* bih_r  = (const float*)d_in[9];
    const float* bhh_r  = (const float*)d_in[10];
    const float* attn_w = (const float*)d_in[11];
    const float* attn_b = (const float*)d_in[12];
    const float* W_ao   = (const float*)d_in[13];
    const float* b_ao   = (const float*)d_in[14];
    const float* W_o    = (const float*)d_in[15];
    const float* b_o    = (const float*)d_in[16];
    float* out = (float*)d_out;

    char* ws = (char*)d_ws;
    __bf16* pk_emb = (__bf16*)(ws + OFF_PK_EMB);
    __bf16* pk_ih  = (__bf16*)(ws + OFF_PK_IH);
    signed char* wq = (signed char*)(ws + OFF_WQ);
    float*  wsc    = (float*)(ws + OFF_WSC);
    __bf16* pk_ao  = (__bf16*)(ws + OFF_PK_AO);
    __bf16* pk_o   = (__bf16*)(ws + OFF_PK_O);
    __bf16* day    = (__bf16*)(ws + OFF_DAY);
    __bf16* Gi     = (__bf16*)(ws + OFF_GIT);
    float*  bc     = (float*)(ws + OFF_BC);
    __bf16* revb   = (__bf16*)(ws + OFF_REV);
    __bf16* fwdb   = (__bf16*)(ws + OFF_FWD);
    __bf16* ht     = (__bf16*)(ws + OFF_HT);
    __bf16* tmp1   = (__bf16*)(ws + OFF_TMP1);
    __bf16* xb     = (__bf16*)(ws + OFF_XB);     // aliases revb (dead until gru)

    pack_misc<<<5432, 256, 0, stream>>>(W_emb, Wih_r, Wih_f, W_ao, W_o, x,
                                        Whh_r, Whh_f, bih_r, bih_f, bhh_r, bhh_f,
                                        pk_emb, pk_ih, pk_ao, pk_o, xb, wq, wsc, bc);

    // R6: day/ao gemms column-split to 2 blocks/CU (NTILES 4->2, grid.y 4->8)
    gemm_k<0, 4096, 2, 256, 256><<<dim3(64, 8), 256, 0, stream>>>(xb, pk_emb, day, b_emb);
    gemm_k<0, 256, 4, 1536, 1536><<<dim3(64, 24), 256, 0, stream>>>(day, pk_ih, Gi, bc);

    gru_recurrent<<<130, 512, 0, stream>>>(wq, wsc, bhh_r, bhh_f, Gi, revb, fwdb);

    attn_kernel<<<256, 512, 0, stream>>>(revb, fwdb, attn_w, attn_b, ht);

    gemm_k<0, 1024, 2, 256, 256><<<dim3(64, 8), 256, 0, stream>>>(ht, pk_ao, tmp1, b_ao);
    gemm_k<1, 256, 4, 942, 942><<<dim3(64, 15), 256, 0, stream>>>(tmp1, pk_o, out, b_o);
}